// Round 7
// baseline (218.815 us; speedup 1.0000x reference)
//
#include <hip/hip_runtime.h>
#include <math.h>

#define B_ 4
#define N_ 1024
#define D_ 768
#define L_ 16
#define DC_ 192
#define EPSF 1e-7f

typedef unsigned long long ull;

// ---------------- kernel 1: start/end head + sx/ex projections (v4) ----------
// (unchanged — ~7 µs)
__global__ __launch_bounds__(256) void head_kernel(
    const float* __restrict__ x, const int* __restrict__ start, const int* __restrict__ end,
    const int* __restrict__ seqlen,
    const float* __restrict__ w_se, const float* __restrict__ b_se,
    const float* __restrict__ w_sp, const float* __restrict__ b_sp,
    float* __restrict__ out_start, float* __restrict__ out_end,
    float* __restrict__ sx_t, float* __restrict__ ex_t,
    int* __restrict__ spi, int* __restrict__ epi,
    float* __restrict__ part_se)
{
  __shared__ float xt[8][D_];     // 24 KB
  __shared__ float xw[DC_][64];   // 48 KB
  __shared__ float smf[4];
  int bid = blockIdx.x;
  int b  = bid >> 7;
  int n0 = (bid & 127) << 3;
  int tid = threadIdx.x;

  {
    float4* xt4 = (float4*)xt;
    const float4* x4 = (const float4*)(x + (size_t)(b * N_ + n0) * D_);
    for (int idx = tid; idx < 8 * D_ / 4; idx += 256) xt4[idx] = x4[idx];
  }

  int col  = tid >> 2;   // 0..63
  int part = tid & 3;
  float acc[8] = {0.f,0.f,0.f,0.f,0.f,0.f,0.f,0.f};

  for (int c = 0; c < D_ / DC_; ++c) {
    int d0 = c * DC_;
    __syncthreads();
    for (int idx = tid; idx < DC_ * 8; idx += 256) {
      int dd = idx >> 3, cc = idx & 7;
      ((float4*)&xw[dd][0])[cc] = ((const float4*)(w_se + (size_t)(d0 + dd) * 32))[cc];
    }
    for (int idx = tid; idx < DC_ * 4; idx += 256) {
      int dd = idx >> 2, cc = idx & 3;
      ((float4*)&xw[dd][32])[cc] = ((const float4*)(w_sp + (size_t)(d0 + dd) * 16))[cc];
      ((float4*)&xw[dd][48])[cc] = ((const float4*)(w_sp + (size_t)(D_ + d0 + dd) * 16))[cc];
    }
    __syncthreads();
    for (int d = part; d < DC_; d += 4) {
      float wv = xw[d][col];
#pragma unroll
      for (int r = 0; r < 8; ++r) acc[r] += xt[r][d0 + d] * wv;
    }
  }

#pragma unroll
  for (int r = 0; r < 8; ++r) {
    acc[r] += __shfl_xor(acc[r], 1, 64);
    acc[r] += __shfl_xor(acc[r], 2, 64);
  }

  float fl = 0.f;
  if (part == 0) {
    int sl = seqlen[b];
    if (col < 32) {
      float bse = b_se[col];
#pragma unroll
      for (int r = 0; r < 8; ++r) {
        int n = n0 + r;
        int mask = (n < sl) ? 1 : 0;
        float z = acc[r] + bse;
        float p = 1.f / (1.f + expf(-z));
        int pred = (z > 0.f && mask) ? 1 : 0;
        int y = (col < L_) ? start[((b * L_ + col) << 10) | n]
                           : end[((b * L_ + (col - L_)) << 10) | n];
        float f = (y == 1) ? (-0.5f * (1.f - p) * (1.f - p) * logf(p + EPSF))
                           : (-0.5f * p * p * logf(1.f - p + EPSF));
        fl += mask ? f : 0.f;
        int o = ((b * L_ + (col & (L_ - 1))) << 10) | n;
        if (col < L_) { out_start[o] = (float)pred; spi[o] = pred; }
        else          { out_end[o]   = (float)pred; epi[o] = pred; }
      }
    } else if (col < 48) {
      int l = col - 32;
      float bb = b_sp[l];
#pragma unroll
      for (int r = 0; r < 8; ++r)
        sx_t[((b * L_ + l) << 10) | (n0 + r)] = acc[r] + bb;
    } else {
      int l = col - 48;
#pragma unroll
      for (int r = 0; r < 8; ++r)
        ex_t[((b * L_ + l) << 10) | (n0 + r)] = acc[r];
    }
  }
  for (int o = 32; o > 0; o >>= 1) fl += __shfl_down(fl, o, 64);
  int wid = tid >> 6, lane = tid & 63;
  if (lane == 0) smf[wid] = fl;
  __syncthreads();
  if (tid == 0) part_se[bid] = smf[0] + smf[1] + smf[2] + smf[3];
}

// ---------------- kernel 2: span sweep (v6 — v3 body + XCD-contiguous swizzle)
// swz = (bid&7)*1024 + bid/8 gives each XCD one contiguous ~33 MB slab of
// span/val/out (and only 8 ex_t/epi rows in its L2). Element math and
// accumulation order identical to v3/v5.
__global__ __launch_bounds__(256) void span_kernel(
    const int* __restrict__ span, const int* __restrict__ val,
    const float* __restrict__ sx_t, const float* __restrict__ ex_t,
    const int* __restrict__ spi, const int* __restrict__ epi,
    float* __restrict__ out_span,
    float* __restrict__ part)
{
  const float L2E = 1.44269504f;
  const float LN2 = 0.69314718f;

  int obid = blockIdx.x;
  int bid  = ((obid & 7) << 10) + (obid >> 3);   // 8192 = 8 * 1024, bijective
  int bl  = bid >> 7;            // b*L + l
  int i0  = (bid & 127) << 3;
  int tid = threadIdx.x;

  float4 e4  = ((const float4*)(ex_t + ((size_t)bl << 10)))[tid];
  int4   ep4 = ((const int4*  )(epi  + ((size_t)bl << 10)))[tid];

  float s_r[8]; int sp_r[8];
#pragma unroll
  for (int r = 0; r < 8; ++r) {
    s_r[r]  = sx_t[(bl << 10) | (i0 + r)];
    sp_r[r] = spi [(bl << 10) | (i0 + r)] ? 1 : 0;
  }

  size_t base = (((size_t)bl << 10) | (size_t)i0) << 10;
  const int4* yrow = (const int4*)(span + base);
  const int4* vrow = (const int4*)(val  + base);
  float4*     orow = (float4*)(out_span + base);

  int j0 = tid << 2;
  float lsum = 0.f;
  int a1 = 0, a2 = 0, a3 = 0;

#pragma unroll
  for (int r = 0; r < 8; ++r) {
    int4 y4 = yrow[r * 256 + tid];
    int4 v4 = vrow[r * 256 + tid];
    int i = i0 + r;
    float s = s_r[r];
    int sp_i = sp_r[r];
    float4 o4;
#pragma unroll
    for (int k = 0; k < 4; ++k) {
      int j   = j0 + k;
      int y   = ((const int*)&y4)[k];
      int vv  = ((const int*)&v4)[k];
      float e = ((const float*)&e4)[k];
      int ep  = ((const int*)&ep4)[k];

      float z  = s + e;
      float em = __builtin_amdgcn_exp2f(z * -L2E);
      float dn = 1.f + em;
      float pr = __builtin_amdgcn_rcpf(dn);
      float U  = __builtin_amdgcn_logf(dn);
      float omp = em * pr;
      bool  yp  = (y != 0);
      float tsel = yp ? omp : pr;
      float Lv   = fmaf(U, LN2, yp ? 0.f : z);
      float fv   = tsel * tsel * Lv;
      lsum += vv ? fv : 0.f;

      int gate = (ep & sp_i) & ((j >= i) ? 1 : 0);
      int predi = (z > 0.f) ? gate : 0;
      ((float*)&o4)[k] = (float)predi;

      a1 += y + (predi << 16);
      a2 += (y & predi) + (vv << 16);
      a3 += (predi == y) ? vv : 0;
    }
    orow[r * 256 + tid] = o4;
  }

  for (int o = 32; o > 0; o >>= 1) {
    lsum += __shfl_down(lsum, o, 64);
    a1   += __shfl_down(a1,   o, 64);
    a2   += __shfl_down(a2,   o, 64);
    a3   += __shfl_down(a3,   o, 64);
  }
  __shared__ float smf[4];
  __shared__ int   smi[3][4];
  int wid = tid >> 6, lane = tid & 63;
  if (lane == 0) { smf[wid] = lsum; smi[0][wid] = a1; smi[1][wid] = a2; smi[2][wid] = a3; }
  __syncthreads();
  if (tid == 0) {
    float ls = smf[0] + smf[1] + smf[2] + smf[3];
    int r1 = smi[0][0] + smi[0][1] + smi[0][2] + smi[0][3];
    int r2 = smi[1][0] + smi[1][1] + smi[1][2] + smi[1][3];
    int r3 = smi[2][0] + smi[2][1] + smi[2][2] + smi[2][3];
    int S_y = r1 & 0xffff, S_p = r1 >> 16;
    int S_yp = r2 & 0xffff, S_v = r2 >> 16;
    float* p = part + (size_t)bid * 8;
    p[0] = 0.5f * ls;
    p[1] = (float)S_v;
    p[2] = (float)r3;
    p[3] = (float)S_yp;
    p[4] = (float)(S_y - S_yp);
    p[5] = (float)(S_p - S_yp);
  }
}

// ---------------- kernel 3: fused reduce + finalize (one block) --------------
// part: [8192][8], part_se: [512]. Per-thread & per-wave sums in float
// (counts <= 4.2M per wave -> exact), final 16-way combine in double.
__global__ __launch_bounds__(1024) void reduce_final_kernel(
    const float* __restrict__ part,
    const float* __restrict__ part_se,
    const int* __restrict__ seqlen,
    float* __restrict__ out_scal)
{
  int tid = threadIdx.x;
  float s[6] = {0.f, 0.f, 0.f, 0.f, 0.f, 0.f};
  for (int r = tid; r < 8192; r += 1024) {
    const float* p = part + (size_t)r * 8;
    s[0] += p[0]; s[1] += p[1]; s[2] += p[2];
    s[3] += p[3]; s[4] += p[4]; s[5] += p[5];
  }
  float se = (tid < 512) ? part_se[tid] : 0.f;

  for (int o = 32; o > 0; o >>= 1) {
    for (int q = 0; q < 6; ++q) s[q] += __shfl_down(s[q], o, 64);
    se += __shfl_down(se, o, 64);
  }
  __shared__ double sm[7][16];
  int wid = tid >> 6, lane = tid & 63;
  if (lane == 0) {
    for (int q = 0; q < 6; ++q) sm[q][wid] = (double)s[q];
    sm[6][wid] = (double)se;
  }
  __syncthreads();
  if (tid == 0) {
    double t[7] = {0,0,0,0,0,0,0};
    for (int w = 0; w < 16; ++w)
      for (int q = 0; q < 7; ++q) t[q] += sm[q][w];
    double masks = 2.0 * L_ * (double)(seqlen[0] + seqlen[1] + seqlen[2] + seqlen[3]);
    double sel  = t[6] / masks;
    double spl  = t[0] / (t[1] + 1e-7);
    double loss = 0.15 * sel + 0.7 * spl;
    out_scal[0] = (float)t[3];  // tp
    out_scal[1] = (float)t[4];  // tn
    out_scal[2] = (float)t[5];  // fp
    out_scal[3] = (float)loss;  // loss
    out_scal[4] = (float)t[2];  // accuracysum
    out_scal[5] = (float)t[1];  // valsum
  }
}

extern "C" void kernel_launch(void* const* d_in, const int* in_sizes, int n_in,
                              void* d_out, int out_size, void* d_ws, size_t ws_size,
                              hipStream_t stream) {
  const float* x      = (const float*)d_in[0];
  const int*   start  = (const int*)  d_in[1];
  const int*   end    = (const int*)  d_in[2];
  const int*   span   = (const int*)  d_in[3];
  const int*   val    = (const int*)  d_in[4];
  const int*   seqlen = (const int*)  d_in[5];
  const float* w_se   = (const float*)d_in[6];
  const float* b_se   = (const float*)d_in[7];
  const float* w_sp   = (const float*)d_in[8];
  const float* b_sp   = (const float*)d_in[9];

  float* out = (float*)d_out;
  const size_t span_elems = (size_t)B_ * L_ * N_ * N_;   // 67,108,864
  const size_t se_elems   = (size_t)B_ * L_ * N_;        // 65,536
  float* out_span  = out;
  float* out_start = out + span_elems;
  float* out_end   = out_start + se_elems;
  float* out_scal  = out_end + se_elems;

  char* ws = (char*)d_ws;
  float*  sx_t    = (float*)(ws + 64);                    // 262144 B
  float*  ex_t    = (float*)(ws + 64 + 262144);           // 262144 B
  int*    spi     = (int*)  (ws + 64 + 2 * 262144);       // 262144 B
  int*    epi     = (int*)  (ws + 64 + 3 * 262144);       // 262144 B
  float*  part    = (float*)(ws + 64 + 4 * 262144);       // 256 KiB
  float*  part_se = (float*)(ws + 64 + 4 * 262144 + 262144); // 512*4 B

  head_kernel<<<512, 256, 0, stream>>>(
      x, start, end, seqlen, w_se, b_se, w_sp, b_sp,
      out_start, out_end, sx_t, ex_t, spi, epi, part_se);

  span_kernel<<<8192, 256, 0, stream>>>(
      span, val, sx_t, ex_t, spi, epi, out_span, part);

  reduce_final_kernel<<<1, 1024, 0, stream>>>(part, part_se, seqlen, out_scal);
}

// Round 8
// 197.937 us; speedup vs baseline: 1.1055x; 1.1055x over previous
//
#include <hip/hip_runtime.h>
#include <math.h>

#define B_ 4
#define N_ 1024
#define D_ 768
#define L_ 16
#define DC_ 192
#define EPSF 1e-7f

typedef unsigned long long ull;

// ---------------- kernel 1: start/end head + sx/ex projections (v4) ----------
// (unchanged — ~7 µs)
__global__ __launch_bounds__(256) void head_kernel(
    const float* __restrict__ x, const int* __restrict__ start, const int* __restrict__ end,
    const int* __restrict__ seqlen,
    const float* __restrict__ w_se, const float* __restrict__ b_se,
    const float* __restrict__ w_sp, const float* __restrict__ b_sp,
    float* __restrict__ out_start, float* __restrict__ out_end,
    float* __restrict__ sx_t, float* __restrict__ ex_t,
    int* __restrict__ spi, int* __restrict__ epi,
    float* __restrict__ part_se)
{
  __shared__ float xt[8][D_];     // 24 KB
  __shared__ float xw[DC_][64];   // 48 KB
  __shared__ float smf[4];
  int bid = blockIdx.x;
  int b  = bid >> 7;
  int n0 = (bid & 127) << 3;
  int tid = threadIdx.x;

  {
    float4* xt4 = (float4*)xt;
    const float4* x4 = (const float4*)(x + (size_t)(b * N_ + n0) * D_);
    for (int idx = tid; idx < 8 * D_ / 4; idx += 256) xt4[idx] = x4[idx];
  }

  int col  = tid >> 2;   // 0..63
  int part = tid & 3;
  float acc[8] = {0.f,0.f,0.f,0.f,0.f,0.f,0.f,0.f};

  for (int c = 0; c < D_ / DC_; ++c) {
    int d0 = c * DC_;
    __syncthreads();
    for (int idx = tid; idx < DC_ * 8; idx += 256) {
      int dd = idx >> 3, cc = idx & 7;
      ((float4*)&xw[dd][0])[cc] = ((const float4*)(w_se + (size_t)(d0 + dd) * 32))[cc];
    }
    for (int idx = tid; idx < DC_ * 4; idx += 256) {
      int dd = idx >> 2, cc = idx & 3;
      ((float4*)&xw[dd][32])[cc] = ((const float4*)(w_sp + (size_t)(d0 + dd) * 16))[cc];
      ((float4*)&xw[dd][48])[cc] = ((const float4*)(w_sp + (size_t)(D_ + d0 + dd) * 16))[cc];
    }
    __syncthreads();
    for (int d = part; d < DC_; d += 4) {
      float wv = xw[d][col];
#pragma unroll
      for (int r = 0; r < 8; ++r) acc[r] += xt[r][d0 + d] * wv;
    }
  }

#pragma unroll
  for (int r = 0; r < 8; ++r) {
    acc[r] += __shfl_xor(acc[r], 1, 64);
    acc[r] += __shfl_xor(acc[r], 2, 64);
  }

  float fl = 0.f;
  if (part == 0) {
    int sl = seqlen[b];
    if (col < 32) {
      float bse = b_se[col];
#pragma unroll
      for (int r = 0; r < 8; ++r) {
        int n = n0 + r;
        int mask = (n < sl) ? 1 : 0;
        float z = acc[r] + bse;
        float p = 1.f / (1.f + expf(-z));
        int pred = (z > 0.f && mask) ? 1 : 0;
        int y = (col < L_) ? start[((b * L_ + col) << 10) | n]
                           : end[((b * L_ + (col - L_)) << 10) | n];
        float f = (y == 1) ? (-0.5f * (1.f - p) * (1.f - p) * logf(p + EPSF))
                           : (-0.5f * p * p * logf(1.f - p + EPSF));
        fl += mask ? f : 0.f;
        int o = ((b * L_ + (col & (L_ - 1))) << 10) | n;
        if (col < L_) { out_start[o] = (float)pred; spi[o] = pred; }
        else          { out_end[o]   = (float)pred; epi[o] = pred; }
      }
    } else if (col < 48) {
      int l = col - 32;
      float bb = b_sp[l];
#pragma unroll
      for (int r = 0; r < 8; ++r)
        sx_t[((b * L_ + l) << 10) | (n0 + r)] = acc[r] + bb;
    } else {
      int l = col - 48;
#pragma unroll
      for (int r = 0; r < 8; ++r)
        ex_t[((b * L_ + l) << 10) | (n0 + r)] = acc[r];
    }
  }
  for (int o = 32; o > 0; o >>= 1) fl += __shfl_down(fl, o, 64);
  int wid = tid >> 6, lane = tid & 63;
  if (lane == 0) smf[wid] = fl;
  __syncthreads();
  if (tid == 0) part_se[bid] = smf[0] + smf[1] + smf[2] + smf[3];
}

// ---------------- kernel 2: span sweep (v7 == round-2 v2, the measured best) -
// grid = B*L*N blocks (one (b,l,i) row each), 256 threads, 4 j's per thread.
__global__ __launch_bounds__(256) void span_kernel(
    const int* __restrict__ span, const int* __restrict__ val,
    const float* __restrict__ sx_t, const float* __restrict__ ex_t,
    const int* __restrict__ spi, const int* __restrict__ epi,
    float* __restrict__ out_span,
    float* __restrict__ part)
{
  const float L2E = 1.44269504f;
  const float LN2 = 0.69314718f;

  int bid = blockIdx.x;            // (b*L + l)*N + i
  int i  = bid & (N_ - 1);
  int bl = bid >> 10;              // b*L + l
  size_t rowoff = (size_t)bid * N_;
  float s   = sx_t[(bl << 10) | i];
  int  sp_i = spi [(bl << 10) | i] ? 1 : 0;

  int tid = threadIdx.x;
  int4   y4  = ((const int4*  )(span + rowoff))[tid];
  int4   v4  = ((const int4*  )(val  + rowoff))[tid];
  float4 e4  = ((const float4*)(ex_t + ((size_t)bl << 10)))[tid];
  int4   ep4 = ((const int4*  )(epi  + ((size_t)bl << 10)))[tid];

  int j0 = tid << 2;
  float lsum = 0.f;
  int a1 = 0;   // S_y | S_pred<<16
  int a2 = 0;   // S_(y&pred) | S_val<<16
  int a3 = 0;   // S_acc (val-gated pred==y)
  float4 o4;

#pragma unroll
  for (int k = 0; k < 4; ++k) {
    int j   = j0 + k;
    int y   = ((const int*)&y4)[k];
    int vv  = ((const int*)&v4)[k];
    float e = ((const float*)&e4)[k];
    int ep  = ((const int*)&ep4)[k];

    float z  = s + e;
    float em = __builtin_amdgcn_exp2f(z * -L2E);
    float dn = 1.f + em;
    float pr = __builtin_amdgcn_rcpf(dn);     // p
    float U  = __builtin_amdgcn_logf(dn);     // log2(1+em)
    float omp = em * pr;                      // 1-p
    bool  yp  = (y != 0);
    float tsel = yp ? omp : pr;
    float Lv   = fmaf(U, LN2, yp ? 0.f : z);  // -ln(p) or -ln(1-p)
    float fv   = tsel * tsel * Lv;            // 2*focal (0.5 folded at end)
    lsum += vv ? fv : 0.f;

    int gate = (ep & sp_i) & ((j >= i) ? 1 : 0);
    int predi = (z > 0.f) ? gate : 0;
    ((float*)&o4)[k] = (float)predi;

    a1 += y + (predi << 16);
    a2 += (y & predi) + (vv << 16);
    a3 += (predi == y) ? vv : 0;
  }
  ((float4*)(out_span + rowoff))[tid] = o4;

  for (int o = 32; o > 0; o >>= 1) {
    lsum += __shfl_down(lsum, o, 64);
    a1   += __shfl_down(a1,   o, 64);
    a2   += __shfl_down(a2,   o, 64);
    a3   += __shfl_down(a3,   o, 64);
  }
  __shared__ float smf[4];
  __shared__ int   smi[3][4];
  int wid = tid >> 6, lane = tid & 63;
  if (lane == 0) { smf[wid] = lsum; smi[0][wid] = a1; smi[1][wid] = a2; smi[2][wid] = a3; }
  __syncthreads();
  if (tid == 0) {
    float ls = smf[0] + smf[1] + smf[2] + smf[3];
    int r1 = smi[0][0] + smi[0][1] + smi[0][2] + smi[0][3];
    int r2 = smi[1][0] + smi[1][1] + smi[1][2] + smi[1][3];
    int r3 = smi[2][0] + smi[2][1] + smi[2][2] + smi[2][3];
    int S_y = r1 & 0xffff, S_p = r1 >> 16;
    int S_yp = r2 & 0xffff, S_v = r2 >> 16;
    float* p = part + (size_t)bid * 8;
    p[0] = 0.5f * ls;               // focal loss partial
    p[1] = (float)S_v;              // val sum
    p[2] = (float)r3;               // accuracy sum
    p[3] = (float)S_yp;             // tp
    p[4] = (float)(S_y - S_yp);     // tn
    p[5] = (float)(S_p - S_yp);     // fp
  }
}

// ---------------- kernel 3: reduce partials into double accumulators --------
// part: [65536][8], part_se: [512]
// acc layout: [0] se_loss, [1] sp_loss, [2] val, [3] accsum, [4] tp, [5] tn, [6] fp
__global__ __launch_bounds__(256) void reduce_kernel(
    const float* __restrict__ part,
    const float* __restrict__ part_se,
    double* __restrict__ acc)
{
  int g = blockIdx.x;  // 0..63
  float s[6] = {0.f, 0.f, 0.f, 0.f, 0.f, 0.f};
  int base = g * 1024;
  for (int r = threadIdx.x; r < 1024; r += 256) {
    const float* p = part + (size_t)(base + r) * 8;
    s[0] += p[0]; s[1] += p[1]; s[2] += p[2];
    s[3] += p[3]; s[4] += p[4]; s[5] += p[5];
  }
  float se = (threadIdx.x < 8) ? part_se[g * 8 + threadIdx.x] : 0.f;

  for (int o = 32; o > 0; o >>= 1) {
    for (int q = 0; q < 6; ++q) s[q] += __shfl_down(s[q], o, 64);
    se += __shfl_down(se, o, 64);
  }
  __shared__ float smf[7][4];
  int wid = threadIdx.x >> 6, lane = threadIdx.x & 63;
  if (lane == 0) { for (int q = 0; q < 6; ++q) smf[q][wid] = s[q]; smf[6][wid] = se; }
  __syncthreads();
  if (threadIdx.x == 0) {
    atomicAdd(&acc[1], (double)(smf[0][0] + smf[0][1] + smf[0][2] + smf[0][3]));
    atomicAdd(&acc[2], (double)(smf[1][0] + smf[1][1] + smf[1][2] + smf[1][3]));
    atomicAdd(&acc[3], (double)(smf[2][0] + smf[2][1] + smf[2][2] + smf[2][3]));
    atomicAdd(&acc[4], (double)(smf[3][0] + smf[3][1] + smf[3][2] + smf[3][3]));
    atomicAdd(&acc[5], (double)(smf[4][0] + smf[4][1] + smf[4][2] + smf[4][3]));
    atomicAdd(&acc[6], (double)(smf[5][0] + smf[5][1] + smf[5][2] + smf[5][3]));
    atomicAdd(&acc[0], (double)(smf[6][0] + smf[6][1] + smf[6][2] + smf[6][3]));
  }
}

// ---------------- kernel 4: finalize scalars ----------------
__global__ void finalize_kernel(const double* __restrict__ acc,
                                const int* __restrict__ seqlen,
                                float* __restrict__ out_scal)
{
  if (threadIdx.x == 0) {
    double masks = 2.0 * L_ * (double)(seqlen[0] + seqlen[1] + seqlen[2] + seqlen[3]);
    double sel  = acc[0] / masks;
    double spl  = acc[1] / (acc[2] + 1e-7);
    double loss = 0.15 * sel + 0.7 * spl;
    out_scal[0] = (float)acc[4];  // tp
    out_scal[1] = (float)acc[5];  // tn
    out_scal[2] = (float)acc[6];  // fp
    out_scal[3] = (float)loss;    // loss
    out_scal[4] = (float)acc[3];  // accuracysum
    out_scal[5] = (float)acc[2];  // valsum
  }
}

extern "C" void kernel_launch(void* const* d_in, const int* in_sizes, int n_in,
                              void* d_out, int out_size, void* d_ws, size_t ws_size,
                              hipStream_t stream) {
  const float* x      = (const float*)d_in[0];
  const int*   start  = (const int*)  d_in[1];
  const int*   end    = (const int*)  d_in[2];
  const int*   span   = (const int*)  d_in[3];
  const int*   val    = (const int*)  d_in[4];
  const int*   seqlen = (const int*)  d_in[5];
  const float* w_se   = (const float*)d_in[6];
  const float* b_se   = (const float*)d_in[7];
  const float* w_sp   = (const float*)d_in[8];
  const float* b_sp   = (const float*)d_in[9];

  float* out = (float*)d_out;
  const size_t span_elems = (size_t)B_ * L_ * N_ * N_;   // 67,108,864
  const size_t se_elems   = (size_t)B_ * L_ * N_;        // 65,536
  float* out_span  = out;
  float* out_start = out + span_elems;
  float* out_end   = out_start + se_elems;
  float* out_scal  = out_end + se_elems;

  char* ws = (char*)d_ws;
  double* acc     = (double*)ws;                          // 8 doubles (64 B)
  float*  sx_t    = (float*)(ws + 64);                    // 262144 B
  float*  ex_t    = (float*)(ws + 64 + 262144);           // 262144 B
  int*    spi     = (int*)  (ws + 64 + 2 * 262144);       // 262144 B
  int*    epi     = (int*)  (ws + 64 + 3 * 262144);       // 262144 B
  float*  part    = (float*)(ws + 64 + 4 * 262144);       // 65536*8*4 = 2 MiB
  float*  part_se = (float*)(ws + 64 + 4 * 262144 + 2097152); // 512*4 B

  (void)hipMemsetAsync(acc, 0, 64, stream);

  head_kernel<<<512, 256, 0, stream>>>(
      x, start, end, seqlen, w_se, b_se, w_sp, b_sp,
      out_start, out_end, sx_t, ex_t, spi, epi, part_se);

  span_kernel<<<B_ * L_ * N_, 256, 0, stream>>>(
      span, val, sx_t, ex_t, spi, epi, out_span, part);

  reduce_kernel<<<64, 256, 0, stream>>>(part, part_se, acc);

  finalize_kernel<<<1, 64, 0, stream>>>(acc, seqlen, out_scal);
}

// Round 9
// 188.412 us; speedup vs baseline: 1.1614x; 1.0506x over previous
//
#include <hip/hip_runtime.h>
#include <math.h>

#define B_ 4
#define N_ 1024
#define D_ 768
#define L_ 16
#define DC_ 192
#define EPSF 1e-7f

typedef unsigned long long ull;

// ---------------- kernel 1: start/end head + sx/ex projections (v4) ----------
// (unchanged — ~7 µs)
__global__ __launch_bounds__(256) void head_kernel(
    const float* __restrict__ x, const int* __restrict__ start, const int* __restrict__ end,
    const int* __restrict__ seqlen,
    const float* __restrict__ w_se, const float* __restrict__ b_se,
    const float* __restrict__ w_sp, const float* __restrict__ b_sp,
    float* __restrict__ out_start, float* __restrict__ out_end,
    float* __restrict__ sx_t, float* __restrict__ ex_t,
    int* __restrict__ spi, int* __restrict__ epi,
    float* __restrict__ part_se)
{
  __shared__ float xt[8][D_];     // 24 KB
  __shared__ float xw[DC_][64];   // 48 KB
  __shared__ float smf[4];
  int bid = blockIdx.x;
  int b  = bid >> 7;
  int n0 = (bid & 127) << 3;
  int tid = threadIdx.x;

  {
    float4* xt4 = (float4*)xt;
    const float4* x4 = (const float4*)(x + (size_t)(b * N_ + n0) * D_);
    for (int idx = tid; idx < 8 * D_ / 4; idx += 256) xt4[idx] = x4[idx];
  }

  int col  = tid >> 2;   // 0..63
  int part = tid & 3;
  float acc[8] = {0.f,0.f,0.f,0.f,0.f,0.f,0.f,0.f};

  for (int c = 0; c < D_ / DC_; ++c) {
    int d0 = c * DC_;
    __syncthreads();
    for (int idx = tid; idx < DC_ * 8; idx += 256) {
      int dd = idx >> 3, cc = idx & 7;
      ((float4*)&xw[dd][0])[cc] = ((const float4*)(w_se + (size_t)(d0 + dd) * 32))[cc];
    }
    for (int idx = tid; idx < DC_ * 4; idx += 256) {
      int dd = idx >> 2, cc = idx & 3;
      ((float4*)&xw[dd][32])[cc] = ((const float4*)(w_sp + (size_t)(d0 + dd) * 16))[cc];
      ((float4*)&xw[dd][48])[cc] = ((const float4*)(w_sp + (size_t)(D_ + d0 + dd) * 16))[cc];
    }
    __syncthreads();
    for (int d = part; d < DC_; d += 4) {
      float wv = xw[d][col];
#pragma unroll
      for (int r = 0; r < 8; ++r) acc[r] += xt[r][d0 + d] * wv;
    }
  }

#pragma unroll
  for (int r = 0; r < 8; ++r) {
    acc[r] += __shfl_xor(acc[r], 1, 64);
    acc[r] += __shfl_xor(acc[r], 2, 64);
  }

  float fl = 0.f;
  if (part == 0) {
    int sl = seqlen[b];
    if (col < 32) {
      float bse = b_se[col];
#pragma unroll
      for (int r = 0; r < 8; ++r) {
        int n = n0 + r;
        int mask = (n < sl) ? 1 : 0;
        float z = acc[r] + bse;
        float p = 1.f / (1.f + expf(-z));
        int pred = (z > 0.f && mask) ? 1 : 0;
        int y = (col < L_) ? start[((b * L_ + col) << 10) | n]
                           : end[((b * L_ + (col - L_)) << 10) | n];
        float f = (y == 1) ? (-0.5f * (1.f - p) * (1.f - p) * logf(p + EPSF))
                           : (-0.5f * p * p * logf(1.f - p + EPSF));
        fl += mask ? f : 0.f;
        int o = ((b * L_ + (col & (L_ - 1))) << 10) | n;
        if (col < L_) { out_start[o] = (float)pred; spi[o] = pred; }
        else          { out_end[o]   = (float)pred; epi[o] = pred; }
      }
    } else if (col < 48) {
      int l = col - 32;
      float bb = b_sp[l];
#pragma unroll
      for (int r = 0; r < 8; ++r)
        sx_t[((b * L_ + l) << 10) | (n0 + r)] = acc[r] + bb;
    } else {
      int l = col - 48;
#pragma unroll
      for (int r = 0; r < 8; ++r)
        ex_t[((b * L_ + l) << 10) | (n0 + r)] = acc[r];
    }
  }
  for (int o = 32; o > 0; o >>= 1) fl += __shfl_down(fl, o, 64);
  int wid = tid >> 6, lane = tid & 63;
  if (lane == 0) smf[wid] = fl;
  __syncthreads();
  if (tid == 0) part_se[bid] = smf[0] + smf[1] + smf[2] + smf[3];
}

// ---------------- kernel 2: span sweep (v7 — measured-best structure) --------
// (unchanged)
__global__ __launch_bounds__(256) void span_kernel(
    const int* __restrict__ span, const int* __restrict__ val,
    const float* __restrict__ sx_t, const float* __restrict__ ex_t,
    const int* __restrict__ spi, const int* __restrict__ epi,
    float* __restrict__ out_span,
    float* __restrict__ part)
{
  const float L2E = 1.44269504f;
  const float LN2 = 0.69314718f;

  int bid = blockIdx.x;            // (b*L + l)*N + i
  int i  = bid & (N_ - 1);
  int bl = bid >> 10;              // b*L + l
  size_t rowoff = (size_t)bid * N_;
  float s   = sx_t[(bl << 10) | i];
  int  sp_i = spi [(bl << 10) | i] ? 1 : 0;

  int tid = threadIdx.x;
  int4   y4  = ((const int4*  )(span + rowoff))[tid];
  int4   v4  = ((const int4*  )(val  + rowoff))[tid];
  float4 e4  = ((const float4*)(ex_t + ((size_t)bl << 10)))[tid];
  int4   ep4 = ((const int4*  )(epi  + ((size_t)bl << 10)))[tid];

  int j0 = tid << 2;
  float lsum = 0.f;
  int a1 = 0;   // S_y | S_pred<<16
  int a2 = 0;   // S_(y&pred) | S_val<<16
  int a3 = 0;   // S_acc (val-gated pred==y)
  float4 o4;

#pragma unroll
  for (int k = 0; k < 4; ++k) {
    int j   = j0 + k;
    int y   = ((const int*)&y4)[k];
    int vv  = ((const int*)&v4)[k];
    float e = ((const float*)&e4)[k];
    int ep  = ((const int*)&ep4)[k];

    float z  = s + e;
    float em = __builtin_amdgcn_exp2f(z * -L2E);
    float dn = 1.f + em;
    float pr = __builtin_amdgcn_rcpf(dn);     // p
    float U  = __builtin_amdgcn_logf(dn);     // log2(1+em)
    float omp = em * pr;                      // 1-p
    bool  yp  = (y != 0);
    float tsel = yp ? omp : pr;
    float Lv   = fmaf(U, LN2, yp ? 0.f : z);  // -ln(p) or -ln(1-p)
    float fv   = tsel * tsel * Lv;            // 2*focal (0.5 folded at end)
    lsum += vv ? fv : 0.f;

    int gate = (ep & sp_i) & ((j >= i) ? 1 : 0);
    int predi = (z > 0.f) ? gate : 0;
    ((float*)&o4)[k] = (float)predi;

    a1 += y + (predi << 16);
    a2 += (y & predi) + (vv << 16);
    a3 += (predi == y) ? vv : 0;
  }
  ((float4*)(out_span + rowoff))[tid] = o4;

  for (int o = 32; o > 0; o >>= 1) {
    lsum += __shfl_down(lsum, o, 64);
    a1   += __shfl_down(a1,   o, 64);
    a2   += __shfl_down(a2,   o, 64);
    a3   += __shfl_down(a3,   o, 64);
  }
  __shared__ float smf[4];
  __shared__ int   smi[3][4];
  int wid = tid >> 6, lane = tid & 63;
  if (lane == 0) { smf[wid] = lsum; smi[0][wid] = a1; smi[1][wid] = a2; smi[2][wid] = a3; }
  __syncthreads();
  if (tid == 0) {
    float ls = smf[0] + smf[1] + smf[2] + smf[3];
    int r1 = smi[0][0] + smi[0][1] + smi[0][2] + smi[0][3];
    int r2 = smi[1][0] + smi[1][1] + smi[1][2] + smi[1][3];
    int r3 = smi[2][0] + smi[2][1] + smi[2][2] + smi[2][3];
    int S_y = r1 & 0xffff, S_p = r1 >> 16;
    int S_yp = r2 & 0xffff, S_v = r2 >> 16;
    float* p = part + (size_t)bid * 8;
    p[0] = 0.5f * ls;               // focal loss partial
    p[1] = (float)S_v;              // val sum
    p[2] = (float)r3;               // accuracy sum
    p[3] = (float)S_yp;             // tp
    p[4] = (float)(S_y - S_yp);     // tn
    p[5] = (float)(S_p - S_yp);     // fp
  }
}

// ---------------- kernel 3: reduce partials (no atomics, no memset) ----------
// part: [65536][8], part_se: [512] -> part2: [64][8]
// Per-group float sums are exact for counts (< 2^24 per group); loss partial
// grouping identical to prior passing rounds.
__global__ __launch_bounds__(256) void reduce_kernel(
    const float* __restrict__ part,
    const float* __restrict__ part_se,
    float* __restrict__ part2)
{
  int g = blockIdx.x;  // 0..63
  float s[6] = {0.f, 0.f, 0.f, 0.f, 0.f, 0.f};
  int base = g * 1024;
  for (int r = threadIdx.x; r < 1024; r += 256) {
    const float* p = part + (size_t)(base + r) * 8;
    s[0] += p[0]; s[1] += p[1]; s[2] += p[2];
    s[3] += p[3]; s[4] += p[4]; s[5] += p[5];
  }
  float se = (threadIdx.x < 8) ? part_se[g * 8 + threadIdx.x] : 0.f;

  for (int o = 32; o > 0; o >>= 1) {
    for (int q = 0; q < 6; ++q) s[q] += __shfl_down(s[q], o, 64);
    se += __shfl_down(se, o, 64);
  }
  __shared__ float smf[7][4];
  int wid = threadIdx.x >> 6, lane = threadIdx.x & 63;
  if (lane == 0) { for (int q = 0; q < 6; ++q) smf[q][wid] = s[q]; smf[6][wid] = se; }
  __syncthreads();
  if (threadIdx.x == 0) {
    float* p2 = part2 + g * 8;
    p2[0] = smf[0][0] + smf[0][1] + smf[0][2] + smf[0][3];  // sp_loss
    p2[1] = smf[1][0] + smf[1][1] + smf[1][2] + smf[1][3];  // val
    p2[2] = smf[2][0] + smf[2][1] + smf[2][2] + smf[2][3];  // accsum
    p2[3] = smf[3][0] + smf[3][1] + smf[3][2] + smf[3][3];  // tp
    p2[4] = smf[4][0] + smf[4][1] + smf[4][2] + smf[4][3];  // tn
    p2[5] = smf[5][0] + smf[5][1] + smf[5][2] + smf[5][3];  // fp
    p2[6] = smf[6][0] + smf[6][1] + smf[6][2] + smf[6][3];  // se_loss
  }
}

// ---------------- kernel 4: finalize (64 lanes, double shuffle-reduce) -------
__global__ void finalize_kernel(const float* __restrict__ part2,
                                const int* __restrict__ seqlen,
                                float* __restrict__ out_scal)
{
  int lane = threadIdx.x;   // 64 threads = 1 wave
  double t[7];
  const float* p2 = part2 + lane * 8;
  for (int q = 0; q < 7; ++q) t[q] = (double)p2[q];
  for (int o = 32; o > 0; o >>= 1)
    for (int q = 0; q < 7; ++q) t[q] += __shfl_down(t[q], o, 64);
  if (lane == 0) {
    double masks = 2.0 * L_ * (double)(seqlen[0] + seqlen[1] + seqlen[2] + seqlen[3]);
    double sel  = t[6] / masks;
    double spl  = t[0] / (t[1] + 1e-7);
    double loss = 0.15 * sel + 0.7 * spl;
    out_scal[0] = (float)t[3];  // tp
    out_scal[1] = (float)t[4];  // tn
    out_scal[2] = (float)t[5];  // fp
    out_scal[3] = (float)loss;  // loss
    out_scal[4] = (float)t[2];  // accuracysum
    out_scal[5] = (float)t[1];  // valsum
  }
}

extern "C" void kernel_launch(void* const* d_in, const int* in_sizes, int n_in,
                              void* d_out, int out_size, void* d_ws, size_t ws_size,
                              hipStream_t stream) {
  const float* x      = (const float*)d_in[0];
  const int*   start  = (const int*)  d_in[1];
  const int*   end    = (const int*)  d_in[2];
  const int*   span   = (const int*)  d_in[3];
  const int*   val    = (const int*)  d_in[4];
  const int*   seqlen = (const int*)  d_in[5];
  const float* w_se   = (const float*)d_in[6];
  const float* b_se   = (const float*)d_in[7];
  const float* w_sp   = (const float*)d_in[8];
  const float* b_sp   = (const float*)d_in[9];

  float* out = (float*)d_out;
  const size_t span_elems = (size_t)B_ * L_ * N_ * N_;   // 67,108,864
  const size_t se_elems   = (size_t)B_ * L_ * N_;        // 65,536
  float* out_span  = out;
  float* out_start = out + span_elems;
  float* out_end   = out_start + se_elems;
  float* out_scal  = out_end + se_elems;

  char* ws = (char*)d_ws;
  float*  sx_t    = (float*)(ws + 64);                    // 262144 B
  float*  ex_t    = (float*)(ws + 64 + 262144);           // 262144 B
  int*    spi     = (int*)  (ws + 64 + 2 * 262144);       // 262144 B
  int*    epi     = (int*)  (ws + 64 + 3 * 262144);       // 262144 B
  float*  part    = (float*)(ws + 64 + 4 * 262144);       // 65536*8*4 = 2 MiB
  float*  part_se = (float*)(ws + 64 + 4 * 262144 + 2097152);     // 512*4 B
  float*  part2   = (float*)(ws + 64 + 4 * 262144 + 2097152 + 4096); // 64*8*4 B

  head_kernel<<<512, 256, 0, stream>>>(
      x, start, end, seqlen, w_se, b_se, w_sp, b_sp,
      out_start, out_end, sx_t, ex_t, spi, epi, part_se);

  span_kernel<<<B_ * L_ * N_, 256, 0, stream>>>(
      span, val, sx_t, ex_t, spi, epi, out_span, part);

  reduce_kernel<<<64, 256, 0, stream>>>(part, part_se, part2);

  finalize_kernel<<<1, 64, 0, stream>>>(part2, seqlen, out_scal);
}

// Round 10
// 167.538 us; speedup vs baseline: 1.3061x; 1.1246x over previous
//
#include <hip/hip_runtime.h>
#include <math.h>

#define B_ 4
#define N_ 1024
#define D_ 768
#define L_ 16
#define DC_ 192
#define EPSF 1e-7f

typedef unsigned long long ull;
typedef int vi4 __attribute__((ext_vector_type(4)));   // native vec for NT load

// ---------------- kernel 1: start/end head + sx/ex projections (v4) ----------
// (unchanged — ~7 µs)
__global__ __launch_bounds__(256) void head_kernel(
    const float* __restrict__ x, const int* __restrict__ start, const int* __restrict__ end,
    const int* __restrict__ seqlen,
    const float* __restrict__ w_se, const float* __restrict__ b_se,
    const float* __restrict__ w_sp, const float* __restrict__ b_sp,
    float* __restrict__ out_start, float* __restrict__ out_end,
    float* __restrict__ sx_t, float* __restrict__ ex_t,
    int* __restrict__ spi, int* __restrict__ epi,
    float* __restrict__ part_se)
{
  __shared__ float xt[8][D_];     // 24 KB
  __shared__ float xw[DC_][64];   // 48 KB
  __shared__ float smf[4];
  int bid = blockIdx.x;
  int b  = bid >> 7;
  int n0 = (bid & 127) << 3;
  int tid = threadIdx.x;

  {
    float4* xt4 = (float4*)xt;
    const float4* x4 = (const float4*)(x + (size_t)(b * N_ + n0) * D_);
    for (int idx = tid; idx < 8 * D_ / 4; idx += 256) xt4[idx] = x4[idx];
  }

  int col  = tid >> 2;   // 0..63
  int part = tid & 3;
  float acc[8] = {0.f,0.f,0.f,0.f,0.f,0.f,0.f,0.f};

  for (int c = 0; c < D_ / DC_; ++c) {
    int d0 = c * DC_;
    __syncthreads();
    for (int idx = tid; idx < DC_ * 8; idx += 256) {
      int dd = idx >> 3, cc = idx & 7;
      ((float4*)&xw[dd][0])[cc] = ((const float4*)(w_se + (size_t)(d0 + dd) * 32))[cc];
    }
    for (int idx = tid; idx < DC_ * 4; idx += 256) {
      int dd = idx >> 2, cc = idx & 3;
      ((float4*)&xw[dd][32])[cc] = ((const float4*)(w_sp + (size_t)(d0 + dd) * 16))[cc];
      ((float4*)&xw[dd][48])[cc] = ((const float4*)(w_sp + (size_t)(D_ + d0 + dd) * 16))[cc];
    }
    __syncthreads();
    for (int d = part; d < DC_; d += 4) {
      float wv = xw[d][col];
#pragma unroll
      for (int r = 0; r < 8; ++r) acc[r] += xt[r][d0 + d] * wv;
    }
  }

#pragma unroll
  for (int r = 0; r < 8; ++r) {
    acc[r] += __shfl_xor(acc[r], 1, 64);
    acc[r] += __shfl_xor(acc[r], 2, 64);
  }

  float fl = 0.f;
  if (part == 0) {
    int sl = seqlen[b];
    if (col < 32) {
      float bse = b_se[col];
#pragma unroll
      for (int r = 0; r < 8; ++r) {
        int n = n0 + r;
        int mask = (n < sl) ? 1 : 0;
        float z = acc[r] + bse;
        float p = 1.f / (1.f + expf(-z));
        int pred = (z > 0.f && mask) ? 1 : 0;
        int y = (col < L_) ? start[((b * L_ + col) << 10) | n]
                           : end[((b * L_ + (col - L_)) << 10) | n];
        float f = (y == 1) ? (-0.5f * (1.f - p) * (1.f - p) * logf(p + EPSF))
                           : (-0.5f * p * p * logf(1.f - p + EPSF));
        fl += mask ? f : 0.f;
        int o = ((b * L_ + (col & (L_ - 1))) << 10) | n;
        if (col < L_) { out_start[o] = (float)pred; spi[o] = pred; }
        else          { out_end[o]   = (float)pred; epi[o] = pred; }
      }
    } else if (col < 48) {
      int l = col - 32;
      float bb = b_sp[l];
#pragma unroll
      for (int r = 0; r < 8; ++r)
        sx_t[((b * L_ + l) << 10) | (n0 + r)] = acc[r] + bb;
    } else {
      int l = col - 48;
#pragma unroll
      for (int r = 0; r < 8; ++r)
        ex_t[((b * L_ + l) << 10) | (n0 + r)] = acc[r];
    }
  }
  for (int o = 32; o > 0; o >>= 1) fl += __shfl_down(fl, o, 64);
  int wid = tid >> 6, lane = tid & 63;
  if (lane == 0) smf[wid] = fl;
  __syncthreads();
  if (tid == 0) part_se[bid] = smf[0] + smf[1] + smf[2] + smf[3];
}

// ---------------- kernel 2: span sweep (v8 — v7 + NT loads on span/val) ------
// Only change vs the passing v7: span/val loads are non-temporal (evict-first)
// so L3 stops retaining half the read stream across replays; HBM then sees a
// dense sequential read stream instead of a scattered one.
__global__ __launch_bounds__(256) void span_kernel(
    const int* __restrict__ span, const int* __restrict__ val,
    const float* __restrict__ sx_t, const float* __restrict__ ex_t,
    const int* __restrict__ spi, const int* __restrict__ epi,
    float* __restrict__ out_span,
    float* __restrict__ part)
{
  const float L2E = 1.44269504f;
  const float LN2 = 0.69314718f;

  int bid = blockIdx.x;            // (b*L + l)*N + i
  int i  = bid & (N_ - 1);
  int bl = bid >> 10;              // b*L + l
  size_t rowoff = (size_t)bid * N_;
  float s   = sx_t[(bl << 10) | i];
  int  sp_i = spi [(bl << 10) | i] ? 1 : 0;

  int tid = threadIdx.x;
  vi4    y4  = __builtin_nontemporal_load((const vi4*)(span + rowoff) + tid);
  vi4    v4  = __builtin_nontemporal_load((const vi4*)(val  + rowoff) + tid);
  float4 e4  = ((const float4*)(ex_t + ((size_t)bl << 10)))[tid];
  int4   ep4 = ((const int4*  )(epi  + ((size_t)bl << 10)))[tid];

  int j0 = tid << 2;
  float lsum = 0.f;
  int a1 = 0;   // S_y | S_pred<<16
  int a2 = 0;   // S_(y&pred) | S_val<<16
  int a3 = 0;   // S_acc (val-gated pred==y)
  float4 o4;

#pragma unroll
  for (int k = 0; k < 4; ++k) {
    int j   = j0 + k;
    int y   = y4[k];
    int vv  = v4[k];
    float e = ((const float*)&e4)[k];
    int ep  = ((const int*)&ep4)[k];

    float z  = s + e;
    float em = __builtin_amdgcn_exp2f(z * -L2E);
    float dn = 1.f + em;
    float pr = __builtin_amdgcn_rcpf(dn);     // p
    float U  = __builtin_amdgcn_logf(dn);     // log2(1+em)
    float omp = em * pr;                      // 1-p
    bool  yp  = (y != 0);
    float tsel = yp ? omp : pr;
    float Lv   = fmaf(U, LN2, yp ? 0.f : z);  // -ln(p) or -ln(1-p)
    float fv   = tsel * tsel * Lv;            // 2*focal (0.5 folded at end)
    lsum += vv ? fv : 0.f;

    int gate = (ep & sp_i) & ((j >= i) ? 1 : 0);
    int predi = (z > 0.f) ? gate : 0;
    ((float*)&o4)[k] = (float)predi;

    a1 += y + (predi << 16);
    a2 += (y & predi) + (vv << 16);
    a3 += (predi == y) ? vv : 0;
  }
  ((float4*)(out_span + rowoff))[tid] = o4;

  for (int o = 32; o > 0; o >>= 1) {
    lsum += __shfl_down(lsum, o, 64);
    a1   += __shfl_down(a1,   o, 64);
    a2   += __shfl_down(a2,   o, 64);
    a3   += __shfl_down(a3,   o, 64);
  }
  __shared__ float smf[4];
  __shared__ int   smi[3][4];
  int wid = tid >> 6, lane = tid & 63;
  if (lane == 0) { smf[wid] = lsum; smi[0][wid] = a1; smi[1][wid] = a2; smi[2][wid] = a3; }
  __syncthreads();
  if (tid == 0) {
    float ls = smf[0] + smf[1] + smf[2] + smf[3];
    int r1 = smi[0][0] + smi[0][1] + smi[0][2] + smi[0][3];
    int r2 = smi[1][0] + smi[1][1] + smi[1][2] + smi[1][3];
    int r3 = smi[2][0] + smi[2][1] + smi[2][2] + smi[2][3];
    int S_y = r1 & 0xffff, S_p = r1 >> 16;
    int S_yp = r2 & 0xffff, S_v = r2 >> 16;
    float* p = part + (size_t)bid * 8;
    p[0] = 0.5f * ls;               // focal loss partial
    p[1] = (float)S_v;              // val sum
    p[2] = (float)r3;               // accuracy sum
    p[3] = (float)S_yp;             // tp
    p[4] = (float)(S_y - S_yp);     // tn
    p[5] = (float)(S_p - S_yp);     // fp
  }
}

// ---------------- kernel 3: reduce partials (no atomics, no memset) ----------
__global__ __launch_bounds__(256) void reduce_kernel(
    const float* __restrict__ part,
    const float* __restrict__ part_se,
    float* __restrict__ part2)
{
  int g = blockIdx.x;  // 0..63
  float s[6] = {0.f, 0.f, 0.f, 0.f, 0.f, 0.f};
  int base = g * 1024;
  for (int r = threadIdx.x; r < 1024; r += 256) {
    const float* p = part + (size_t)(base + r) * 8;
    s[0] += p[0]; s[1] += p[1]; s[2] += p[2];
    s[3] += p[3]; s[4] += p[4]; s[5] += p[5];
  }
  float se = (threadIdx.x < 8) ? part_se[g * 8 + threadIdx.x] : 0.f;

  for (int o = 32; o > 0; o >>= 1) {
    for (int q = 0; q < 6; ++q) s[q] += __shfl_down(s[q], o, 64);
    se += __shfl_down(se, o, 64);
  }
  __shared__ float smf[7][4];
  int wid = threadIdx.x >> 6, lane = threadIdx.x & 63;
  if (lane == 0) { for (int q = 0; q < 6; ++q) smf[q][wid] = s[q]; smf[6][wid] = se; }
  __syncthreads();
  if (threadIdx.x == 0) {
    float* p2 = part2 + g * 8;
    p2[0] = smf[0][0] + smf[0][1] + smf[0][2] + smf[0][3];  // sp_loss
    p2[1] = smf[1][0] + smf[1][1] + smf[1][2] + smf[1][3];  // val
    p2[2] = smf[2][0] + smf[2][1] + smf[2][2] + smf[2][3];  // accsum
    p2[3] = smf[3][0] + smf[3][1] + smf[3][2] + smf[3][3];  // tp
    p2[4] = smf[4][0] + smf[4][1] + smf[4][2] + smf[4][3];  // tn
    p2[5] = smf[5][0] + smf[5][1] + smf[5][2] + smf[5][3];  // fp
    p2[6] = smf[6][0] + smf[6][1] + smf[6][2] + smf[6][3];  // se_loss
  }
}

// ---------------- kernel 4: finalize (64 lanes, double shuffle-reduce) -------
__global__ void finalize_kernel(const float* __restrict__ part2,
                                const int* __restrict__ seqlen,
                                float* __restrict__ out_scal)
{
  int lane = threadIdx.x;   // 64 threads = 1 wave
  double t[7];
  const float* p2 = part2 + lane * 8;
  for (int q = 0; q < 7; ++q) t[q] = (double)p2[q];
  for (int o = 32; o > 0; o >>= 1)
    for (int q = 0; q < 7; ++q) t[q] += __shfl_down(t[q], o, 64);
  if (lane == 0) {
    double masks = 2.0 * L_ * (double)(seqlen[0] + seqlen[1] + seqlen[2] + seqlen[3]);
    double sel  = t[6] / masks;
    double spl  = t[0] / (t[1] + 1e-7);
    double loss = 0.15 * sel + 0.7 * spl;
    out_scal[0] = (float)t[3];  // tp
    out_scal[1] = (float)t[4];  // tn
    out_scal[2] = (float)t[5];  // fp
    out_scal[3] = (float)loss;  // loss
    out_scal[4] = (float)t[2];  // accuracysum
    out_scal[5] = (float)t[1];  // valsum
  }
}

extern "C" void kernel_launch(void* const* d_in, const int* in_sizes, int n_in,
                              void* d_out, int out_size, void* d_ws, size_t ws_size,
                              hipStream_t stream) {
  const float* x      = (const float*)d_in[0];
  const int*   start  = (const int*)  d_in[1];
  const int*   end    = (const int*)  d_in[2];
  const int*   span   = (const int*)  d_in[3];
  const int*   val    = (const int*)  d_in[4];
  const int*   seqlen = (const int*)  d_in[5];
  const float* w_se   = (const float*)d_in[6];
  const float* b_se   = (const float*)d_in[7];
  const float* w_sp   = (const float*)d_in[8];
  const float* b_sp   = (const float*)d_in[9];

  float* out = (float*)d_out;
  const size_t span_elems = (size_t)B_ * L_ * N_ * N_;   // 67,108,864
  const size_t se_elems   = (size_t)B_ * L_ * N_;        // 65,536
  float* out_span  = out;
  float* out_start = out + span_elems;
  float* out_end   = out_start + se_elems;
  float* out_scal  = out_end + se_elems;

  char* ws = (char*)d_ws;
  float*  sx_t    = (float*)(ws + 64);                    // 262144 B
  float*  ex_t    = (float*)(ws + 64 + 262144);           // 262144 B
  int*    spi     = (int*)  (ws + 64 + 2 * 262144);       // 262144 B
  int*    epi     = (int*)  (ws + 64 + 3 * 262144);       // 262144 B
  float*  part    = (float*)(ws + 64 + 4 * 262144);       // 65536*8*4 = 2 MiB
  float*  part_se = (float*)(ws + 64 + 4 * 262144 + 2097152);     // 512*4 B
  float*  part2   = (float*)(ws + 64 + 4 * 262144 + 2097152 + 4096); // 64*8*4 B

  head_kernel<<<512, 256, 0, stream>>>(
      x, start, end, seqlen, w_se, b_se, w_sp, b_sp,
      out_start, out_end, sx_t, ex_t, spi, epi, part_se);

  span_kernel<<<B_ * L_ * N_, 256, 0, stream>>>(
      span, val, sx_t, ex_t, spi, epi, out_span, part);

  reduce_kernel<<<64, 256, 0, stream>>>(part, part_se, part2);

  finalize_kernel<<<1, 64, 0, stream>>>(part2, seqlen, out_scal);
}